// Round 21
// baseline (673.972 us; speedup 1.0000x reference)
//
#include <hip/hip_runtime.h>

#define E 1024
#define H 4096
#define NLAYER 24
#define V 50277
#define NB 256
#define NT 1024
#define LN_EPS 1e-5f

typedef unsigned long long u64;

// ---- LDS float offsets (dynamic shared, 160032 B) ----
// R1 (16 slots x 1024): A(l) rows (w<12: mat w>>2, row bid*4+(w&3)) -> fkw(l) -> A(l+1)
// R2 (4 rows x 4096): fvw(l) row r=w>>2, chunk w&3 -- wave-private
#define R1O    0
#define R2O    16384
#define POOLO  32768   // 4096: xk|xv|xr|wkv (A/B); fxk (C); fk (D)
#define SXO    36864   // 1024
#define SSXO   37888   // 1024
#define FXRO   38912   // 1024
#define REDO   39936   // 32
#define PARTO  39968   // 16 (k dots 0-3, v dots 4-7)
#define BACCO  39984   // 4 (ow partial accum)
#define DACCO  39988   // 4 (fvw partial accum)
#define FACCO  39992   // 4 (frw partial accum)
#define CNTO   39996   // 12 uints: acnt[4], bcnt[4], dcnt[4]
#define SMEMF  40008

struct Params {
  const float* emb;   const float* ln0_w; const float* ln0_b;
  const float* ln1_w; const float* ln1_b;
  const float* tmk;   const float* tmv;   const float* tmr;
  const float* tf;    const float* td;
  const float* kw;    const float* vw;    const float* rw;  const float* ow;
  const float* ln2_w; const float* ln2_b;
  const float* ftmk;  const float* ftmr;
  const float* fkw;   const float* fvw;   const float* frw;
  const float* lnow;  const float* lnob;  const float* headw;
  const float* st;    const int* tok;
  float* out; float* ws;
};

// ---- tagged 8-byte dataflow handoff (relaxed agent scope) ----
__device__ __forceinline__ void stg_tag(u64* p, float v, unsigned tag) {
  u64 w = ((u64)__float_as_uint(v) << 32) | (u64)tag;
  __hip_atomic_store(p, w, __ATOMIC_RELAXED, __HIP_MEMORY_SCOPE_AGENT);
}
__device__ __forceinline__ u64 ld_tag(const u64* p) {
  return __hip_atomic_load(p, __ATOMIC_RELAXED, __HIP_MEMORY_SCOPE_AGENT);
}
__device__ __forceinline__ float poll_tag(const u64* p, unsigned tag) {
  u64 w = ld_tag(p);
  while ((unsigned)w != tag) { __builtin_amdgcn_s_sleep(1); w = ld_tag(p); }
  return __uint_as_float((unsigned)(w >> 32));
}

__device__ __forceinline__ void wait_pf() {
  asm volatile("s_waitcnt vmcnt(0)" ::: "memory");
}

// zero-VGPR global->LDS DMA: 64 lanes x 16 B = 1 KB per call.
__device__ __forceinline__ void gload_lds16(const float* g, float* l) {
  __builtin_amdgcn_global_load_lds(
      (const __attribute__((address_space(1))) unsigned int*)(g),
      (__attribute__((address_space(3))) unsigned int*)(l), 16, 0, 0);
}
__device__ __forceinline__ void pf_row4k(const float* row, float* dst, int lane) {
#pragma unroll
  for (int c = 0; c < 4; ++c)
    gload_lds16(row + c * 256 + lane * 4, dst + c * 256);
}

__device__ __forceinline__ float warp_sum(float v) {
#pragma unroll
  for (int off = 32; off; off >>= 1) v += __shfl_down(v, off);
  return v;
}

// single-sync LN stats: returns (mean, var)
__device__ __forceinline__ float2 ln_stats(float v, float* red) {
  float a = v, b = v * v;
#pragma unroll
  for (int off = 32; off; off >>= 1) { a += __shfl_xor(a, off); b += __shfl_xor(b, off); }
  const int wid = threadIdx.x >> 6, lane = threadIdx.x & 63;
  if (lane == 0) { red[2 * wid] = a; red[2 * wid + 1] = b; }
  __syncthreads();
  float s1 = 0.f, s2 = 0.f;
  const float2* r2 = (const float2*)red;
#pragma unroll
  for (int j = 0; j < 16; ++j) { float2 t = r2[j]; s1 += t.x; s2 += t.y; }
  float m = s1 * (1.f / E);
  return make_float2(m, s2 * (1.f / E) - m * m);
}

__device__ __forceinline__ float dot4(float4 a, float4 b) {
  return a.x * b.x + a.y * b.y + a.z * b.z + a.w * b.w;
}

__device__ __forceinline__ float dotlds(const float* wrow, const float* vec, int lane) {
  const float4* w4 = (const float4*)wrow;
  const float4* v4 = (const float4*)vec;
  float acc = 0.f;
#pragma unroll
  for (int p = 0; p < 4; ++p)
    acc += dot4(w4[lane + p * 64], v4[lane + p * 64]);
  return warp_sum(acc);
}

__global__ __launch_bounds__(NT, 1) void rwkv_kernel(Params p) {
  const int tid = threadIdx.x, bid = blockIdx.x;
  const int lane = tid & 63, wid = tid >> 6;

  extern __shared__ float smem[];
  float* r1     = smem + R1O;
  float* r2     = smem + R2O;
  float* pool   = smem + POOLO;
  float* s_x    = smem + SXO;
  float* s_sx   = smem + SSXO;
  float* s_fxr  = smem + FXRO;
  float* s_red  = smem + REDO;
  float* s_part = smem + PARTO;
  float* s_bacc = smem + BACCO;
  float* s_dacc = smem + DACCO;
  float* s_facc = smem + FACCO;
  unsigned* s_acnt = (unsigned*)(smem + CNTO);
  unsigned* s_bcnt = (unsigned*)(smem + CNTO) + 4;
  unsigned* s_dcnt = (unsigned*)(smem + CNTO) + 8;

  u64* tws = (u64*)p.ws;
  u64* twk = tws;             // [2][E]  (wkv handoff)
  u64* tsx = tws + 6 * E;
  u64* tx  = tws + 8 * E;
  u64* tfk = tws + 10 * E;    // [2][H]

  float* out_st = p.out + V;
  const int token = p.tok[0];

  // wave->work mappings
  const bool hasA = wid < 12;
  const int matA = wid >> 2;                     // 0:kw 1:vw 2:rw  (wid<12)
  const int rowA = bid * 4 + (wid & 3);          // LOCAL rows: block owns its 4 elems
  const int rloc = wid >> 2, kc = wid & 3;       // ow/frw/fvw: row bid*4+rloc, chunk kc
  const int rowO = bid * 4 + rloc;
  float* wA = r1 + wid * 1024;                   // wave-private R1 slot
  float* wD = r2 + rloc * 4096 + kc * 1024;      // wave-private R2 slot

  // zero atomic-combine scratch (covered by LN0's internal barrier)
  if (tid < 24) smem[BACCO + tid] = 0.f;

  // ---- init: A(0) DMA ----
  if (hasA) {
    const float* W = (matA == 0 ? p.kw : matA == 1 ? p.vw : p.rw) + (size_t)rowA * E;
    pf_row4k(W, wA, lane);
  }

  // LN0
  {
    float v = p.emb[(size_t)token * E + tid];
    float2 mv = ln_stats(v, s_red);
    s_x[tid] = (v - mv.x) / sqrtf(mv.y + LN_EPS) * p.ln0_w[tid] + p.ln0_b[tid];
  }

  for (int l = 0; l < NLAYER; ++l) {
    const float* stl = p.st + (size_t)5 * l * E;
    float* ostl = out_st + (size_t)5 * l * E;
    const int par = l & 1;
    const unsigned tg = (unsigned)(l + 1);

    // ================ Phase A: LN1 + mix + k/v/r dots + LOCAL WKV ================
    // param loads issued before the poll -> they stream during the wait
    float l1w = p.ln1_w[l * E + tid], l1b = p.ln1_b[l * E + tid];
    float ax = stl[E + tid];
    float ta = p.tmk[l * E + tid], tb = p.tmv[l * E + tid], tc = p.tmr[l * E + tid];
    // WKV owners = lane 0 of r-waves (wid 8-11); preload state+params (hidden)
    float aav = 0.f, bbv = 0.f, ppv = 0.f, tfv = 0.f, tdv = 0.f;
    const int eOwn = bid * 4 + (wid & 3);
    if (wid >= 8 && wid < 12 && lane == 0) {
      aav = stl[2 * E + eOwn]; bbv = stl[3 * E + eOwn]; ppv = stl[4 * E + eOwn];
      tfv = p.tf[l * E + eOwn]; tdv = p.td[l * E + eOwn];
    }
    float xv_;
    if (l > 0) { xv_ = poll_tag(&tx[par * E + tid], (unsigned)l); s_x[tid] = xv_; }
    else       { xv_ = s_x[tid]; }
    {
      float2 mv = ln_stats(xv_, s_red);                       // SYNC 1
      float xn = (xv_ - mv.x) / sqrtf(mv.y + LN_EPS) * l1w + l1b;
      pool[tid]        = xn * ta + ax * (1.f - ta);           // xk
      pool[1024 + tid] = xn * tb + ax * (1.f - tb);           // xv
      pool[2048 + tid] = xn * tc + ax * (1.f - tc);           // xr
      if (bid == 0) ostl[E + tid] = xn;                       // new att_x
    }
    __syncthreads();                                          // SYNC 2
    wait_pf();   // l==0: init DMA; l>0: no-op (drained by tx poll)
    if (hasA) {
      float d = dotlds(wA, pool + matA * 1024, lane);
      if (matA < 2) {                   // k (waves 0-3) / v (waves 4-7) producers
        if (lane == 0) {
          s_part[wid] = d;              // k at [e], v at [4+e]
          atomicAdd(&s_acnt[wid & 3], 1u);
        }
      } else if (lane == 0) {           // r-wave = WKV owner for elem (wid&3)
        const int e = wid & 3;
        while (*(volatile unsigned*)&s_acnt[e] < 2u) __builtin_amdgcn_s_sleep(1);
        asm volatile("" ::: "memory");
        float kk = s_part[e], vv = s_part[4 + e];
        float rr = 1.f / (1.f + expf(-d));
        float wwv = tfv + kk;
        float pm = fmaxf(ppv, wwv);
        float e1 = expf(ppv - pm), e2 = expf(wwv - pm);
        float a = e1 * aav + e2 * vv, b = e1 * bbv + e2;
        stg_tag(&twk[par * E + eOwn], rr * a / b, tg);
        float ww2 = ppv + tdv;
        float p2 = fmaxf(ww2, kk);
        float f1 = expf(ww2 - p2), f2 = expf(kk - p2);
        ostl[2 * E + eOwn] = f1 * aav + f2 * vv;              // naa
        ostl[3 * E + eOwn] = f1 * bbv + f2;                   // nbb
        ostl[4 * E + eOwn] = p2;                              // npp
        *(volatile unsigned*)&s_acnt[e] = 0u;                 // reset for next layer
      }
    }

    // ================ Phase B: wkv poll + ow matvec ================
    {
      // 1) register load + DMA issued before the poll (stream during wait)
      float4 wow = ((const float4*)(p.ow + (size_t)l * E * E + (size_t)rowO * E + kc * 256))[lane];
      pf_row4k(p.fkw + (size_t)l * H * E + (size_t)(bid * 16 + wid) * E, wA, lane);
      // 2) poll own wkv element (single tag, single producer)
      pool[3072 + tid] = poll_tag(&twk[par * E + tid], tg);
      __syncthreads();                                        // SYNC 3 (wkv ready)
      const float4* v4 = (const float4*)(pool + 3072 + kc * 256);
      float acc = warp_sum(dot4(wow, v4[lane]));
      if (lane == 0) {                  // last-adder combine, no barrier
        atomicAdd(&s_bacc[rloc], acc);
        unsigned old = atomicAdd(&s_bcnt[rloc], 1u);
        if (old == 3u) {
          asm volatile("" ::: "memory");
          float dsum = *(volatile float*)&s_bacc[rloc];
          stg_tag(&tsx[par * E + bid * 4 + rloc], s_x[bid * 4 + rloc] + dsum, tg);
          *(volatile float*)&s_bacc[rloc] = 0.f;
          *(volatile unsigned*)&s_bcnt[rloc] = 0u;
        }
      }
    }

    // ================ Phase C: LN2 + mix + fkw matvec + frw partials ================
    {
      // 1) small register loads (land during the poll wait)
      float l2w = p.ln2_w[l * E + tid], l2b = p.ln2_b[l * E + tid];
      float fx = stl[tid];
      float fa = p.ftmk[l * E + tid], fb = p.ftmr[l * E + tid];
      float4 wfr = ((const float4*)(p.frw + (size_t)l * E * E + (size_t)rowO * E + kc * 256))[lane];
      // 2) DMA for phase D: fvw chunk (streams during the poll wait; wD wave-private)
      pf_row4k(p.fvw + (size_t)l * E * H + (size_t)rowO * H + kc * 1024, wD, lane);
      // 3) poll sx
      float sxv = poll_tag(&tsx[par * E + tid], tg);
      s_sx[tid] = sxv;
      // 4) LN2 + mix
      float2 mv = ln_stats(sxv, s_red);                       // SYNC 5
      float xn2 = (sxv - mv.x) / sqrtf(mv.y + LN_EPS) * l2w + l2b;
      pool[tid]  = xn2 * fa + fx * (1.f - fa);                // fxk
      s_fxr[tid] = xn2 * fb + fx * (1.f - fb);
      if (bid == 0) ostl[tid] = xn2;                          // new ffn_x
      __syncthreads();                                        // SYNC 6
      float d = dotlds(wA, pool, lane);                       // fkw row (resident)
      if (lane == 0) { float t = fmaxf(d, 0.f); stg_tag(&tfk[par * H + bid * 16 + wid], t * t, tg); }
      const float4* f4 = (const float4*)(s_fxr + kc * 256);
      float fp = warp_sum(dot4(wfr, f4[lane]));               // frw partial
      if (lane == 0) atomicAdd(&s_facc[rloc], fp);            // gated by D's counter+barriers
    }

    // ================ Phase D: fvw matvec + residual ================
    // issue A(l+1) DMA first (own R1 slot; fkw dot completed in program order)
    if (l + 1 < NLAYER && hasA) {
      const float* W = (matA == 0 ? p.kw : matA == 1 ? p.vw : p.rw) +
                       (size_t)(l + 1) * E * E + (size_t)rowA * E;
      pf_row4k(W, wA, lane);
    }
    __syncthreads();             // SYNC 7: close C's pool/s_fxr reads before relay
    {
      // poll fk (drains C's fvw DMA + A' DMA -- both streamed during waits)
      const u64* base = tfk + par * H;
      u64 w0 = ld_tag(base + tid);
      u64 w1 = ld_tag(base + tid + 1024);
      u64 w2 = ld_tag(base + tid + 2048);
      u64 w3 = ld_tag(base + tid + 3072);
      while ((unsigned)w0 != tg) { __builtin_amdgcn_s_sleep(1); w0 = ld_tag(base + tid); }
      while ((unsigned)w1 != tg) { __builtin_amdgcn_s_sleep(1); w1 = ld_tag(base + tid + 1024); }
      while ((unsigned)w2 != tg) { __builtin_amdgcn_s_sleep(1); w2 = ld_tag(base + tid + 2048); }
      while ((unsigned)w3 != tg) { __builtin_amdgcn_s_sleep(1); w3 = ld_tag(base + tid + 3072); }
      pool[tid]        = __uint_as_float((unsigned)(w0 >> 32));
      pool[tid + 1024] = __uint_as_float((unsigned)(w1 >> 32));
      pool[tid + 2048] = __uint_as_float((unsigned)(w2 >> 32));
      pool[tid + 3072] = __uint_as_float((unsigned)(w3 >> 32));
    }
    __syncthreads();             // SYNC 8: fk relay complete
    {
      const float4* v4 = (const float4*)(pool + kc * 1024);
      const float4* w4 = (const float4*)wD;                   // own slot (drained)
      float acc = 0.f;
#pragma unroll
      for (int pc = 0; pc < 4; ++pc)
        acc += dot4(w4[lane + pc * 64], v4[lane + pc * 64]);
      acc = warp_sum(acc);
      if (lane == 0) {                  // last-adder combine, no barrier
        atomicAdd(&s_dacc[rloc], acc);
        unsigned old = atomicAdd(&s_dcnt[rloc], 1u);
        if (old == 3u) {
          asm volatile("" ::: "memory");
          float dsum = *(volatile float*)&s_dacc[rloc];
          float frs  = *(volatile float*)&s_facc[rloc];       // all frw adds done (SYNC 7/8)
          float fr = 1.f / (1.f + expf(-frs));
          stg_tag(&tx[((l + 1) & 1) * E + bid * 4 + rloc],
                  s_sx[bid * 4 + rloc] + fr * dsum, tg);
          *(volatile float*)&s_dacc[rloc] = 0.f;
          *(volatile float*)&s_facc[rloc] = 0.f;
          *(volatile unsigned*)&s_dcnt[rloc] = 0u;
        }
      }
    }
  }

  // ================ Head: LN_out + V x E matvec (4-way rows) ================
  {
    float xv_ = poll_tag(&tx[(NLAYER & 1) * E + tid], (unsigned)NLAYER);
    float2 mv = ln_stats(xv_, s_red);
    pool[tid] = (xv_ - mv.x) / sqrtf(mv.y + LN_EPS) * p.lnow[tid] + p.lnob[tid];
  }
  __syncthreads();
  {
    const int gw = bid * 16 + wid;
    const float4* v4 = (const float4*)pool;
    float4 x0 = v4[lane], x1 = v4[lane + 64], x2 = v4[lane + 128], x3 = v4[lane + 192];
    int row = gw;
    for (; row + 12288 < V; row += 16384) {
      const float4* W0 = (const float4*)(p.headw + (size_t)row * E);
      const float4* W1 = (const float4*)(p.headw + (size_t)(row + 4096) * E);
      const float4* W2 = (const float4*)(p.headw + (size_t)(row + 8192) * E);
      const float4* W3 = (const float4*)(p.headw + (size_t)(row + 12288) * E);
      float a0 = 0.f, a1 = 0.f, a2 = 0.f, a3 = 0.f;
      a0 += dot4(W0[lane], x0) + dot4(W0[lane + 64], x1) + dot4(W0[lane + 128], x2) + dot4(W0[lane + 192], x3);
      a1 += dot4(W1[lane], x0) + dot4(W1[lane + 64], x1) + dot4(W1[lane + 128], x2) + dot4(W1[lane + 192], x3);
      a2 += dot4(W2[lane], x0) + dot4(W2[lane + 64], x1) + dot4(W2[lane + 128], x2) + dot4(W2[lane + 192], x3);
      a3 += dot4(W3[lane], x0) + dot4(W3[lane + 64], x1) + dot4(W3[lane + 128], x2) + dot4(W3[lane + 192], x3);
      a0 = warp_sum(a0); a1 = warp_sum(a1); a2 = warp_sum(a2); a3 = warp_sum(a3);
      if (lane == 0) {
        p.out[row] = a0; p.out[row + 4096] = a1;
        p.out[row + 8192] = a2; p.out[row + 12288] = a3;
      }
    }
    for (; row < V; row += 4096) {
      const float4* W0 = (const float4*)(p.headw + (size_t)row * E);
      float a0 = dot4(W0[lane], x0) + dot4(W0[lane + 64], x1) +
                 dot4(W0[lane + 128], x2) + dot4(W0[lane + 192], x3);
      a0 = warp_sum(a0);
      if (lane == 0) p.out[row] = a0;
    }
  }
}

extern "C" void kernel_launch(void* const* d_in, const int* in_sizes, int n_in,
                              void* d_out, int out_size, void* d_ws, size_t ws_size,
                              hipStream_t stream) {
  Params p;
  p.emb   = (const float*)d_in[0];
  p.ln0_w = (const float*)d_in[1];
  p.ln0_b = (const float*)d_in[2];
  p.ln1_w = (const float*)d_in[3];
  p.ln1_b = (const float*)d_in[4];
  p.tmk   = (const float*)d_in[5];
  p.tmv   = (const float*)d_in[6];
  p.tmr   = (const float*)d_in[7];
  p.tf    = (const float*)d_in[8];
  p.td    = (const float*)d_in[9];
  p.kw    = (const float*)d_in[10];
  p.vw    = (const float*)d_in[11];
  p.rw    = (const float*)d_in[12];
  p.ow    = (const float*)d_in[13];
  p.ln2_w = (const float*)d_in[14];
  p.ln2_b = (const float*)d_in[15];
  p.ftmk  = (const float*)d_in[16];
  p.ftmr  = (const float*)d_in[17];
  p.fkw   = (const float*)d_in[18];
  p.fvw   = (const float*)d_in[19];
  p.frw   = (const float*)d_in[20];
  p.lnow  = (const float*)d_in[21];
  p.lnob  = (const float*)d_in[22];
  p.headw = (const float*)d_in[23];
  if (in_sizes[24] == 1) {
    p.tok = (const int*)d_in[24];
    p.st  = (const float*)d_in[25];
  } else {
    p.st  = (const float*)d_in[24];
    p.tok = (const int*)d_in[25];
  }
  p.out   = (float*)d_out;
  p.ws    = (float*)d_ws;

  // zero ALL tag words each launch (graph node): (10E + 2H) u64 = 147456 B
  hipMemsetAsync(d_ws, 0, (10 * E + 2 * H) * sizeof(unsigned long long), stream);

  void* args[] = { &p };
  hipLaunchCooperativeKernel((const void*)rwkv_kernel, dim3(NB), dim3(NT),
                             args, SMEMF * sizeof(float), stream);
}

// Round 22
// 488.189 us; speedup vs baseline: 1.3806x; 1.3806x over previous
//
#include <hip/hip_runtime.h>

#define E 1024
#define H 4096
#define NLAYER 24
#define V 50277
#define NB 256
#define NT 1024
#define LN_EPS 1e-5f

typedef unsigned long long u64;

// ---- LDS float offsets (dynamic shared, 160000 B) ----
// R1 (16 slots x 1024): A(l) rows (w<12: mat w>>2, row bid*4+(w&3)) -> fkw(l) -> A(l+1)
// R2 (4 rows x 4096): fvw(l) row r=w>>2, chunk w&3 -- wave-private
#define R1O    0
#define R2O    16384
#define POOLO  32768   // 4096: xk|xv|xr|wkv (A/B); fxk (C); fk (D)
#define SXO    36864   // 1024
#define SSXO   37888   // 1024
#define FXRO   38912   // 1024
#define REDO   39936   // 32
#define PARTO  39968   // 16
#define PART2O 39984   // 16
#define SMEMF  40000

struct Params {
  const float* emb;   const float* ln0_w; const float* ln0_b;
  const float* ln1_w; const float* ln1_b;
  const float* tmk;   const float* tmv;   const float* tmr;
  const float* tf;    const float* td;
  const float* kw;    const float* vw;    const float* rw;  const float* ow;
  const float* ln2_w; const float* ln2_b;
  const float* ftmk;  const float* ftmr;
  const float* fkw;   const float* fvw;   const float* frw;
  const float* lnow;  const float* lnob;  const float* headw;
  const float* st;    const int* tok;
  float* out; float* ws;
};

// ---- tagged 8-byte dataflow handoff (relaxed agent scope) ----
__device__ __forceinline__ void stg_tag(u64* p, float v, unsigned tag) {
  u64 w = ((u64)__float_as_uint(v) << 32) | (u64)tag;
  __hip_atomic_store(p, w, __ATOMIC_RELAXED, __HIP_MEMORY_SCOPE_AGENT);
}
__device__ __forceinline__ u64 ld_tag(const u64* p) {
  return __hip_atomic_load(p, __ATOMIC_RELAXED, __HIP_MEMORY_SCOPE_AGENT);
}
__device__ __forceinline__ float poll_tag(const u64* p, unsigned tag) {
  u64 w = ld_tag(p);
  while ((unsigned)w != tag) { __builtin_amdgcn_s_sleep(1); w = ld_tag(p); }
  return __uint_as_float((unsigned)(w >> 32));
}

__device__ __forceinline__ void wait_pf() {
  asm volatile("s_waitcnt vmcnt(0)" ::: "memory");
}

// zero-VGPR global->LDS DMA: 64 lanes x 16 B = 1 KB per call.
__device__ __forceinline__ void gload_lds16(const float* g, float* l) {
  __builtin_amdgcn_global_load_lds(
      (const __attribute__((address_space(1))) unsigned int*)(g),
      (__attribute__((address_space(3))) unsigned int*)(l), 16, 0, 0);
}
__device__ __forceinline__ void pf_row4k(const float* row, float* dst, int lane) {
#pragma unroll
  for (int c = 0; c < 4; ++c)
    gload_lds16(row + c * 256 + lane * 4, dst + c * 256);
}

__device__ __forceinline__ float warp_sum(float v) {
#pragma unroll
  for (int off = 32; off; off >>= 1) v += __shfl_down(v, off);
  return v;
}

// single-sync LN stats: returns (mean, var)
__device__ __forceinline__ float2 ln_stats(float v, float* red) {
  float a = v, b = v * v;
#pragma unroll
  for (int off = 32; off; off >>= 1) { a += __shfl_xor(a, off); b += __shfl_xor(b, off); }
  const int wid = threadIdx.x >> 6, lane = threadIdx.x & 63;
  if (lane == 0) { red[2 * wid] = a; red[2 * wid + 1] = b; }
  __syncthreads();
  float s1 = 0.f, s2 = 0.f;
  const float2* r2 = (const float2*)red;
#pragma unroll
  for (int j = 0; j < 16; ++j) { float2 t = r2[j]; s1 += t.x; s2 += t.y; }
  float m = s1 * (1.f / E);
  return make_float2(m, s2 * (1.f / E) - m * m);
}

__device__ __forceinline__ float dot4(float4 a, float4 b) {
  return a.x * b.x + a.y * b.y + a.z * b.z + a.w * b.w;
}

__device__ __forceinline__ float dotlds(const float* wrow, const float* vec, int lane) {
  const float4* w4 = (const float4*)wrow;
  const float4* v4 = (const float4*)vec;
  float acc = 0.f;
#pragma unroll
  for (int p = 0; p < 4; ++p)
    acc += dot4(w4[lane + p * 64], v4[lane + p * 64]);
  return warp_sum(acc);
}

__global__ __launch_bounds__(NT, 1) void rwkv_kernel(Params p) {
  const int tid = threadIdx.x, bid = blockIdx.x;
  const int lane = tid & 63, wid = tid >> 6;

  extern __shared__ float smem[];
  float* r1     = smem + R1O;
  float* r2     = smem + R2O;
  float* pool   = smem + POOLO;
  float* s_x    = smem + SXO;
  float* s_sx   = smem + SSXO;
  float* s_fxr  = smem + FXRO;
  float* s_red  = smem + REDO;
  float* s_part = smem + PARTO;
  float* s_part2= smem + PART2O;

  u64* tws = (u64*)p.ws;
  u64* twk = tws;             // [2][E]  (wkv handoff; slots of old tk)
  u64* tsx = tws + 6 * E;
  u64* tx  = tws + 8 * E;
  u64* tfk = tws + 10 * E;    // [2][H]

  float* out_st = p.out + V;
  const int token = p.tok[0];

  // wave->work mappings
  const bool hasA = wid < 12;
  const int matA = wid >> 2;                     // 0:kw 1:vw 2:rw  (wid<12)
  const int rowA = bid * 4 + (wid & 3);          // LOCAL rows: block owns its 4 elems
  const int rloc = wid >> 2, kc = wid & 3;       // ow/frw/fvw: row bid*4+rloc, chunk kc
  const int rowO = bid * 4 + rloc;
  float* wA = r1 + wid * 1024;                   // wave-private R1 slot
  float* wD = r2 + rloc * 4096 + kc * 1024;      // wave-private R2 slot

  // ---- init: A(0) DMA ----
  if (hasA) {
    const float* W = (matA == 0 ? p.kw : matA == 1 ? p.vw : p.rw) + (size_t)rowA * E;
    pf_row4k(W, wA, lane);
  }

  // LN0
  {
    float v = p.emb[(size_t)token * E + tid];
    float2 mv = ln_stats(v, s_red);
    s_x[tid] = (v - mv.x) / sqrtf(mv.y + LN_EPS) * p.ln0_w[tid] + p.ln0_b[tid];
  }

  for (int l = 0; l < NLAYER; ++l) {
    const float* stl = p.st + (size_t)5 * l * E;
    float* ostl = out_st + (size_t)5 * l * E;
    const int par = l & 1;
    const unsigned tg = (unsigned)(l + 1);

    // ================ Phase A: LN1 + mix + k/v/r dots + LOCAL WKV ================
    // param loads issued before the poll -> they stream during the wait
    float l1w = p.ln1_w[l * E + tid], l1b = p.ln1_b[l * E + tid];
    float ax = stl[E + tid];
    float ta = p.tmk[l * E + tid], tb = p.tmv[l * E + tid], tc = p.tmr[l * E + tid];
    // owner threads preload state+params for their element (hidden under poll)
    float aav, bbv, ppv, tfv, tdv;
    const int eOwn = bid * 4 + tid;              // valid when tid<4
    if (tid < 4) {
      aav = stl[2 * E + eOwn]; bbv = stl[3 * E + eOwn]; ppv = stl[4 * E + eOwn];
      tfv = p.tf[l * E + eOwn]; tdv = p.td[l * E + eOwn];
    }
    float xv_;
    if (l > 0) { xv_ = poll_tag(&tx[par * E + tid], (unsigned)l); s_x[tid] = xv_; }
    else       { xv_ = s_x[tid]; }
    {
      float2 mv = ln_stats(xv_, s_red);                       // SYNC 1
      float xn = (xv_ - mv.x) / sqrtf(mv.y + LN_EPS) * l1w + l1b;
      pool[tid]        = xn * ta + ax * (1.f - ta);           // xk
      pool[1024 + tid] = xn * tb + ax * (1.f - tb);           // xv
      pool[2048 + tid] = xn * tc + ax * (1.f - tc);           // xr
      if (bid == 0) ostl[E + tid] = xn;                       // new att_x
    }
    __syncthreads();                                          // SYNC 2
    wait_pf();   // l==0: init DMA; l>0: no-op (drained by tx poll)
    if (hasA) {
      float d = dotlds(wA, pool + matA * 1024, lane);
      if (lane == 0) s_part[wid] = d;           // k:0-3, v:4-7, r:8-11 (elem wid&3)
    }
    __syncthreads();                                          // SYNC 2.5
    if (tid < 4) {    // local WKV for element eOwn; single tag handoff
      float kk = s_part[tid], vv = s_part[4 + tid];
      float rr = 1.f / (1.f + expf(-s_part[8 + tid]));
      float wwv = tfv + kk;
      float pm = fmaxf(ppv, wwv);
      float e1 = expf(ppv - pm), e2 = expf(wwv - pm);
      float a = e1 * aav + e2 * vv, b = e1 * bbv + e2;
      stg_tag(&twk[par * E + eOwn], rr * a / b, tg);
      float ww2 = ppv + tdv;
      float p2 = fmaxf(ww2, kk);
      float f1 = expf(ww2 - p2), f2 = expf(kk - p2);
      ostl[2 * E + eOwn] = f1 * aav + f2 * vv;                // naa
      ostl[3 * E + eOwn] = f1 * bbv + f2;                     // nbb
      ostl[4 * E + eOwn] = p2;                                // npp
    }

    // ================ Phase B: wkv poll + ow matvec ================
    {
      // 1) register load + DMA issued before the poll (stream during wait)
      float4 wow = ((const float4*)(p.ow + (size_t)l * E * E + (size_t)rowO * E + kc * 256))[lane];
      pf_row4k(p.fkw + (size_t)l * H * E + (size_t)(bid * 16 + wid) * E, wA, lane);
      // 2) poll own wkv element (single tag, single producer)
      pool[3072 + tid] = poll_tag(&twk[par * E + tid], tg);
      __syncthreads();                                        // SYNC 3 (wkv ready)
      const float4* v4 = (const float4*)(pool + 3072 + kc * 256);
      float acc = warp_sum(dot4(wow, v4[lane]));
      if (lane == 0) s_part[wid] = acc;
    }
    __syncthreads();                                          // SYNC 4
    if (tid < 4) {
      float dsum = s_part[tid * 4] + s_part[tid * 4 + 1] +
                   s_part[tid * 4 + 2] + s_part[tid * 4 + 3];
      stg_tag(&tsx[par * E + bid * 4 + tid], s_x[bid * 4 + tid] + dsum, tg);
    }

    // ================ Phase C: LN2 + mix + fkw matvec + frw partials ================
    {
      // 1) small register loads (land during the poll wait)
      float l2w = p.ln2_w[l * E + tid], l2b = p.ln2_b[l * E + tid];
      float fx = stl[tid];
      float fa = p.ftmk[l * E + tid], fb = p.ftmr[l * E + tid];
      float4 wfr = ((const float4*)(p.frw + (size_t)l * E * E + (size_t)rowO * E + kc * 256))[lane];
      // 2) DMA for phase D: fvw chunk (streams during the poll wait; wD wave-private)
      pf_row4k(p.fvw + (size_t)l * E * H + (size_t)rowO * H + kc * 1024, wD, lane);
      // 3) poll sx
      float sxv = poll_tag(&tsx[par * E + tid], tg);
      s_sx[tid] = sxv;
      // 4) LN2 + mix
      float2 mv = ln_stats(sxv, s_red);                       // SYNC 5
      float xn2 = (sxv - mv.x) / sqrtf(mv.y + LN_EPS) * l2w + l2b;
      pool[tid]  = xn2 * fa + fx * (1.f - fa);                // fxk
      s_fxr[tid] = xn2 * fb + fx * (1.f - fb);
      if (bid == 0) ostl[tid] = xn2;                          // new ffn_x
      __syncthreads();                                        // SYNC 6
      float d = dotlds(wA, pool, lane);                       // fkw row (resident)
      if (lane == 0) { float t = fmaxf(d, 0.f); stg_tag(&tfk[par * H + bid * 16 + wid], t * t, tg); }
      const float4* f4 = (const float4*)(s_fxr + kc * 256);
      float fp = warp_sum(dot4(wfr, f4[lane]));               // frw partial
      if (lane == 0) s_part2[wid] = fp;
    }

    // ================ Phase D: fvw matvec + residual ================
    // issue A(l+1) DMA first (own R1 slot; fkw dot completed in program order)
    if (l + 1 < NLAYER && hasA) {
      const float* W = (matA == 0 ? p.kw : matA == 1 ? p.vw : p.rw) +
                       (size_t)(l + 1) * E * E + (size_t)rowA * E;
      pf_row4k(W, wA, lane);
    }
    __syncthreads();             // SYNC 7: close C's pool/s_fxr reads before relay
    {
      // poll fk (drains C's fvw DMA + A' DMA -- both streamed during waits)
      const u64* base = tfk + par * H;
      u64 w0 = ld_tag(base + tid);
      u64 w1 = ld_tag(base + tid + 1024);
      u64 w2 = ld_tag(base + tid + 2048);
      u64 w3 = ld_tag(base + tid + 3072);
      while ((unsigned)w0 != tg) { __builtin_amdgcn_s_sleep(1); w0 = ld_tag(base + tid); }
      while ((unsigned)w1 != tg) { __builtin_amdgcn_s_sleep(1); w1 = ld_tag(base + tid + 1024); }
      while ((unsigned)w2 != tg) { __builtin_amdgcn_s_sleep(1); w2 = ld_tag(base + tid + 2048); }
      while ((unsigned)w3 != tg) { __builtin_amdgcn_s_sleep(1); w3 = ld_tag(base + tid + 3072); }
      pool[tid]        = __uint_as_float((unsigned)(w0 >> 32));
      pool[tid + 1024] = __uint_as_float((unsigned)(w1 >> 32));
      pool[tid + 2048] = __uint_as_float((unsigned)(w2 >> 32));
      pool[tid + 3072] = __uint_as_float((unsigned)(w3 >> 32));
    }
    __syncthreads();             // SYNC 8: fk relay complete
    {
      const float4* v4 = (const float4*)(pool + kc * 1024);
      const float4* w4 = (const float4*)wD;                   // own slot (drained)
      float acc = 0.f;
#pragma unroll
      for (int pc = 0; pc < 4; ++pc)
        acc += dot4(w4[lane + pc * 64], v4[lane + pc * 64]);
      acc = warp_sum(acc);
      if (lane == 0) s_part[wid] = acc;
    }
    __syncthreads();             // SYNC 9
    if (tid < 4) {
      float dsum = s_part[tid * 4] + s_part[tid * 4 + 1] +
                   s_part[tid * 4 + 2] + s_part[tid * 4 + 3];
      float frs  = s_part2[tid * 4] + s_part2[tid * 4 + 1] +
                   s_part2[tid * 4 + 2] + s_part2[tid * 4 + 3];
      float fr = 1.f / (1.f + expf(-frs));
      stg_tag(&tx[((l + 1) & 1) * E + bid * 4 + tid],
              s_sx[bid * 4 + tid] + fr * dsum, tg);
    }
  }

  // ================ Head: LN_out + V x E matvec (4-way rows) ================
  {
    float xv_ = poll_tag(&tx[(NLAYER & 1) * E + tid], (unsigned)NLAYER);
    float2 mv = ln_stats(xv_, s_red);
    pool[tid] = (xv_ - mv.x) / sqrtf(mv.y + LN_EPS) * p.lnow[tid] + p.lnob[tid];
  }
  __syncthreads();
  {
    const int gw = bid * 16 + wid;
    const float4* v4 = (const float4*)pool;
    float4 x0 = v4[lane], x1 = v4[lane + 64], x2 = v4[lane + 128], x3 = v4[lane + 192];
    int row = gw;
    for (; row + 12288 < V; row += 16384) {
      const float4* W0 = (const float4*)(p.headw + (size_t)row * E);
      const float4* W1 = (const float4*)(p.headw + (size_t)(row + 4096) * E);
      const float4* W2 = (const float4*)(p.headw + (size_t)(row + 8192) * E);
      const float4* W3 = (const float4*)(p.headw + (size_t)(row + 12288) * E);
      float a0 = 0.f, a1 = 0.f, a2 = 0.f, a3 = 0.f;
      a0 += dot4(W0[lane], x0) + dot4(W0[lane + 64], x1) + dot4(W0[lane + 128], x2) + dot4(W0[lane + 192], x3);
      a1 += dot4(W1[lane], x0) + dot4(W1[lane + 64], x1) + dot4(W1[lane + 128], x2) + dot4(W1[lane + 192], x3);
      a2 += dot4(W2[lane], x0) + dot4(W2[lane + 64], x1) + dot4(W2[lane + 128], x2) + dot4(W2[lane + 192], x3);
      a3 += dot4(W3[lane], x0) + dot4(W3[lane + 64], x1) + dot4(W3[lane + 128], x2) + dot4(W3[lane + 192], x3);
      a0 = warp_sum(a0); a1 = warp_sum(a1); a2 = warp_sum(a2); a3 = warp_sum(a3);
      if (lane == 0) {
        p.out[row] = a0; p.out[row + 4096] = a1;
        p.out[row + 8192] = a2; p.out[row + 12288] = a3;
      }
    }
    for (; row < V; row += 4096) {
      const float4* W0 = (const float4*)(p.headw + (size_t)row * E);
      float a0 = dot4(W0[lane], x0) + dot4(W0[lane + 64], x1) +
                 dot4(W0[lane + 128], x2) + dot4(W0[lane + 192], x3);
      a0 = warp_sum(a0);
      if (lane == 0) p.out[row] = a0;
    }
  }
}

extern "C" void kernel_launch(void* const* d_in, const int* in_sizes, int n_in,
                              void* d_out, int out_size, void* d_ws, size_t ws_size,
                              hipStream_t stream) {
  Params p;
  p.emb   = (const float*)d_in[0];
  p.ln0_w = (const float*)d_in[1];
  p.ln0_b = (const float*)d_in[2];
  p.ln1_w = (const float*)d_in[3];
  p.ln1_b = (const float*)d_in[4];
  p.tmk   = (const float*)d_in[5];
  p.tmv   = (const float*)d_in[6];
  p.tmr   = (const float*)d_in[7];
  p.tf    = (const float*)d_in[8];
  p.td    = (const float*)d_in[9];
  p.kw    = (const float*)d_in[10];
  p.vw    = (const float*)d_in[11];
  p.rw    = (const float*)d_in[12];
  p.ow    = (const float*)d_in[13];
  p.ln2_w = (const float*)d_in[14];
  p.ln2_b = (const float*)d_in[15];
  p.ftmk  = (const float*)d_in[16];
  p.ftmr  = (const float*)d_in[17];
  p.fkw   = (const float*)d_in[18];
  p.fvw   = (const float*)d_in[19];
  p.frw   = (const float*)d_in[20];
  p.lnow  = (const float*)d_in[21];
  p.lnob  = (const float*)d_in[22];
  p.headw = (const float*)d_in[23];
  if (in_sizes[24] == 1) {
    p.tok = (const int*)d_in[24];
    p.st  = (const float*)d_in[25];
  } else {
    p.st  = (const float*)d_in[24];
    p.tok = (const int*)d_in[25];
  }
  p.out   = (float*)d_out;
  p.ws    = (float*)d_ws;

  // zero ALL tag words each launch (graph node): (10E + 2H) u64 = 147456 B
  hipMemsetAsync(d_ws, 0, (10 * E + 2 * H) * sizeof(unsigned long long), stream);

  void* args[] = { &p };
  hipLaunchCooperativeKernel((const void*)rwkv_kernel, dim3(NB), dim3(NT),
                             args, SMEMF * sizeof(float), stream);
}